// Round 4
// baseline (413.244 us; speedup 1.0000x reference)
//
#include <hip/hip_runtime.h>
#include <hip/hip_bf16.h>
#include <stdint.h>

#define BATCH  8192
#define NFEAT  8192
#define DMODEL 1024

typedef unsigned short u16;
typedef __attribute__((ext_vector_type(8))) short  short8;
typedef __attribute__((ext_vector_type(4))) float  f32x4;

// fp32 -> bf16 round-to-nearest-even
__device__ __forceinline__ u16 f2b(float f) {
    uint32_t u = __float_as_uint(f);
    u += 0x7fffu + ((u >> 16) & 1u);
    return (u16)(u >> 16);
}

// async global->LDS, 16B per lane; LDS dest is wave-uniform base + lane*16 (HW rule)
__device__ __forceinline__ void gld16(const u16* g, void* l) {
    __builtin_amdgcn_global_load_lds(
        (const __attribute__((address_space(1))) void*)(uintptr_t)g,
        (__attribute__((address_space(3))) void*)(uint32_t)(uintptr_t)l,
        16, 0, 0);
}

// ---------------- conversion kernels ----------------

__global__ void cvt_x_kernel(const float* __restrict__ x, u16* __restrict__ xb) {
    int i = blockIdx.x * blockDim.x + threadIdx.x;
    const float4* xv = (const float4*)x;
    float4 a = xv[2 * i];
    float4 b = xv[2 * i + 1];
    union { u16 u[8]; uint4 v; } o;
    o.u[0] = f2b(a.x); o.u[1] = f2b(a.y); o.u[2] = f2b(a.z); o.u[3] = f2b(a.w);
    o.u[4] = f2b(b.x); o.u[5] = f2b(b.y); o.u[6] = f2b(b.z); o.u[7] = f2b(b.w);
    ((uint4*)xb)[i] = o.v;
}

__global__ void cvt_w_kernel(const float* __restrict__ W,
                             u16* __restrict__ wb, u16* __restrict__ wt) {
    __shared__ u16 tile[64][65];
    const int f0 = blockIdx.x * 64;
    const int d0 = blockIdx.y * 64;
    const int t  = threadIdx.x;
#pragma unroll
    for (int rep = 0; rep < 16; ++rep) {
        int idx = rep * 256 + t;
        int r = idx >> 6, c = idx & 63;
        float v = W[(size_t)(f0 + r) * DMODEL + d0 + c];
        u16 u = f2b(v);
        tile[r][c] = u;
        wb[(size_t)(f0 + r) * DMODEL + d0 + c] = u;
    }
    __syncthreads();
#pragma unroll
    for (int rep = 0; rep < 16; ++rep) {
        int idx = rep * 256 + t;
        int r = idx >> 6, c = idx & 63;
        wt[(size_t)(d0 + r) * NFEAT + f0 + c] = tile[c][r];
    }
}

#define SYNC_IN()  do { __builtin_amdgcn_sched_barrier(0); __builtin_amdgcn_s_barrier(); \
                        asm volatile("s_waitcnt lgkmcnt(0)" ::: "memory");               \
                        __builtin_amdgcn_sched_barrier(0); } while (0)
#define SYNC_OUT() do { __builtin_amdgcn_s_setprio(0); __builtin_amdgcn_sched_barrier(0); \
                        __builtin_amdgcn_s_barrier(); } while (0)

// ---------------- GEMM 1: 256x128 tile, 8-phase, 8 waves ----------------
// H = A @ B^T (bf16 out). A [M][K], B [N][K]. Grid = (M/256)*(N/128) = 256 blocks.
__global__ __launch_bounds__(512, 2)
void gemm1_8phase(const u16* __restrict__ A, const u16* __restrict__ B,
                  u16* __restrict__ H, int N, int K) {
    const int NT = K >> 6;
    __shared__ __align__(1024) char lds[98304];
    const int BOFF = 65536;

    const int tid  = threadIdx.x;
    const int lane = tid & 63;
    const int wave = tid >> 6;             // 0..7
    const int wm   = wave >> 2;            // 0..1 (128-row half)
    const int wn   = wave & 3;             // 0..3 (32-col group)

    const int nwg = gridDim.x;
    const int swz = (blockIdx.x & 7) * (nwg >> 3) + (blockIdx.x >> 3);
    const int ntn = N >> 7;                // n-blocks (8)
    const int tm0 = (swz / ntn) << 8;
    const int tn0 = (swz % ntn) << 7;

    const int srl = lane >> 2;
    const int sch = (lane & 3) ^ (((lane >> 5) & 1) << 1);
    const int scol  = (wave & 1) * 32 + sch * 8;
    const int srow0 = (wave >> 1) * 16 + srl;

    const u16* pa[2][2];
    pa[0][0] = A + (size_t)(tm0 + srow0)            * K + scol;
    pa[0][1] = A + (size_t)(tm0 + srow0 + 64)       * K + scol;
    pa[1][0] = A + (size_t)(tm0 + 128 + srow0)      * K + scol;
    pa[1][1] = A + (size_t)(tm0 + 128 + srow0 + 64) * K + scol;
    const u16* pb[2];
    pb[0] = B + (size_t)(tn0 + srow0)      * K + scol;
    pb[1] = B + (size_t)(tn0 + srow0 + 64) * K + scol;

    auto STAGE_A = [&](int tau, int half) {
        if (tau < NT) {
            char* d = lds + (tau & 1) * 32768 + half * 16384 + wave * 1024;
            gld16(pa[half][0] + (size_t)tau * 64, d);
            gld16(pa[half][1] + (size_t)tau * 64, d + 8192);
        }
    };
    auto STAGE_B = [&](int tau) {
        if (tau < NT) {
            char* d = lds + BOFF + (tau & 1) * 16384 + wave * 1024;
            gld16(pb[0] + (size_t)tau * 64, d);
            gld16(pb[1] + (size_t)tau * 64, d + 8192);
        }
    };

    const int l15 = lane & 15, lhi = lane >> 4;
    const int pch = lhi ^ (((lane >> 3) & 1) << 1);
    const int lof = l15 * 64 + pch * 16;

    short8 a[4][2];
    short8 b[2][2];
    f32x4  acc[8][2] = {};

    const char* Ab;
    const char* Bb;
    auto LDA_ = [&](int mh) {
#pragma unroll
        for (int fm = 0; fm < 4; ++fm)
#pragma unroll
            for (int ks = 0; ks < 2; ++ks)
                a[fm][ks] = *(const short8*)(Ab + ((mh * 4 + fm) * 2 + ks) * 1024);
    };
    auto LDB_ = [&](int nh) {
#pragma unroll
        for (int ks = 0; ks < 2; ++ks)
            b[nh][ks] = *(const short8*)(Bb + (nh * 2 + ks) * 1024);
    };
    auto MMA_ = [&](int mh, int nh) {
#pragma unroll
        for (int ks = 0; ks < 2; ++ks)
#pragma unroll
            for (int fm = 0; fm < 4; ++fm)
                acc[mh * 4 + fm][nh] = __builtin_amdgcn_mfma_f32_16x16x32_bf16(
                    a[fm][ks], b[nh][ks], acc[mh * 4 + fm][nh], 0, 0, 0);
    };

    STAGE_A(0, 0); STAGE_A(0, 1); STAGE_B(0); STAGE_B(1);
    asm volatile("s_waitcnt vmcnt(2)" ::: "memory");
    __builtin_amdgcn_s_barrier();

    for (int t = 0; t < NT; ++t) {
        Ab = lds + (t & 1) * 32768 + wm * 16384 + lof;
        Bb = lds + BOFF + (t & 1) * 16384 + wn * 4096 + lof;

        LDA_(0); LDB_(0);
        STAGE_A(t + 1, 0);
        SYNC_IN();
        __builtin_amdgcn_s_setprio(1);
        MMA_(0, 0);
        SYNC_OUT();

        LDB_(1);
        STAGE_A(t + 1, 1);
        SYNC_IN();
        __builtin_amdgcn_s_setprio(1);
        MMA_(0, 1);
        SYNC_OUT();

        LDA_(1);
        STAGE_B(t + 2);
        SYNC_IN();
        __builtin_amdgcn_s_setprio(1);
        MMA_(1, 1);
        SYNC_OUT();

        __builtin_amdgcn_sched_barrier(0);
        __builtin_amdgcn_s_barrier();
        __builtin_amdgcn_s_setprio(1);
        MMA_(1, 0);
        __builtin_amdgcn_s_setprio(0);
        __builtin_amdgcn_sched_barrier(0);
        if (t < NT - 2)       asm volatile("s_waitcnt vmcnt(2)" ::: "memory");
        else if (t == NT - 2) asm volatile("s_waitcnt vmcnt(0)" ::: "memory");
        __builtin_amdgcn_s_barrier();
    }

    // ---- epilogue: bf16 tile via LDS transpose, coalesced 16B stores ----
    // tile 256x128 u16 = 64 KiB, fits LDS in one pass. All gld16 drained (vmcnt(0)
    // at t==NT-2, no stages after), all waves barrier-synced -> LDS reusable.
    u16* lu = (u16*)lds;
#pragma unroll
    for (int fm = 0; fm < 8; ++fm)
#pragma unroll
        for (int nh = 0; nh < 2; ++nh) {
            const int col  = wn * 32 + nh * 16 + l15;
            const int row0 = wm * 128 + fm * 16 + lhi * 4;
#pragma unroll
            for (int r = 0; r < 4; ++r)
                lu[(row0 + r) * 128 + col] = f2b(acc[fm][nh][r]);
        }
    __syncthreads();
    const uint4* ls = (const uint4*)lds;
#pragma unroll
    for (int s = 0; s < 8; ++s) {
        int i = s * 512 + tid;            // 4096 uint4 = 64 KiB
        int row = i >> 4;                 // 16 uint4 per 128-u16 row
        int col = (i & 15) * 8;           // u16 col
        *(uint4*)(H + (size_t)(tm0 + row) * N + (tn0 + col)) = ls[i];
    }
}

// ---------------- GEMM 2: 256x256 8-phase ----------------
__global__ __launch_bounds__(512, 2)
void gemm2_8phase(const u16* __restrict__ A, const u16* __restrict__ B,
                  float* __restrict__ O, const float* __restrict__ bias,
                  int N, int K) {
    const int NT = K >> 6;
    __shared__ __align__(1024) char lds[131072];
    const int BOFF = 65536;

    const int tid  = threadIdx.x;
    const int lane = tid & 63;
    const int wave = tid >> 6;
    const int wm   = wave >> 2;
    const int wn   = wave & 3;

    const int nwg = gridDim.x;
    const int swz = (blockIdx.x & 7) * (nwg >> 3) + (blockIdx.x >> 3);
    const int ntn = N >> 8;
    const int tm0 = (swz / ntn) << 8;
    const int tn0 = (swz % ntn) << 8;

    const int srl = lane >> 2;
    const int sch = (lane & 3) ^ (((lane >> 5) & 1) << 1);
    const int scol  = (wave & 1) * 32 + sch * 8;
    const int srow0 = (wave >> 1) * 16 + srl;

    const u16* pa[2][2];
    const u16* pb[2][2];
    pa[0][0] = A + (size_t)(tm0 + srow0)       * K + scol;
    pa[0][1] = A + (size_t)(tm0 + srow0 + 64)  * K + scol;
    pa[1][0] = A + (size_t)(tm0 + 128 + srow0)      * K + scol;
    pa[1][1] = A + (size_t)(tm0 + 128 + srow0 + 64) * K + scol;
    pb[0][0] = B + (size_t)(tn0 + srow0)       * K + scol;
    pb[0][1] = B + (size_t)(tn0 + srow0 + 64)  * K + scol;
    pb[1][0] = B + (size_t)(tn0 + 128 + srow0)      * K + scol;
    pb[1][1] = B + (size_t)(tn0 + 128 + srow0 + 64) * K + scol;

    auto STAGE = [&](int tau, int isB, int half) {
        if (tau < NT) {
            char* d = lds + (isB ? BOFF : 0) + (tau & 1) * 32768 + half * 16384 + wave * 1024;
            const u16* p0 = (isB ? pb[half][0] : pa[half][0]) + (size_t)tau * 64;
            const u16* p1 = (isB ? pb[half][1] : pa[half][1]) + (size_t)tau * 64;
            gld16(p0, d);
            gld16(p1, d + 8192);
        }
    };

    const int l15 = lane & 15, lhi = lane >> 4;
    const int pch = lhi ^ (((lane >> 3) & 1) << 1);
    const int lof = l15 * 64 + pch * 16;

    short8 a[4][2];
    short8 b[4][2];
    f32x4  acc[8][4] = {};

    const char* Ab;
    const char* Bb;
    auto LDA_ = [&](int mh) {
#pragma unroll
        for (int fm = 0; fm < 4; ++fm)
#pragma unroll
            for (int ks = 0; ks < 2; ++ks)
                a[fm][ks] = *(const short8*)(Ab + ((mh * 4 + fm) * 2 + ks) * 1024);
    };
    auto LDB_ = [&](int nh) {
#pragma unroll
        for (int fn = 0; fn < 2; ++fn)
#pragma unroll
            for (int ks = 0; ks < 2; ++ks)
                b[nh * 2 + fn][ks] = *(const short8*)(Bb + (((wn & 1) * 4 + nh * 2 + fn) * 2 + ks) * 1024);
    };
    auto MMA_ = [&](int mh, int nh) {
#pragma unroll
        for (int ks = 0; ks < 2; ++ks)
#pragma unroll
            for (int fm = 0; fm < 4; ++fm)
#pragma unroll
                for (int fn = 0; fn < 2; ++fn)
                    acc[mh * 4 + fm][nh * 2 + fn] = __builtin_amdgcn_mfma_f32_16x16x32_bf16(
                        a[fm][ks], b[nh * 2 + fn][ks], acc[mh * 4 + fm][nh * 2 + fn], 0, 0, 0);
    };

    STAGE(0, 0, 0); STAGE(0, 0, 1); STAGE(0, 1, 0); STAGE(0, 1, 1);
    STAGE(1, 1, 0); STAGE(1, 1, 1);
    asm volatile("s_waitcnt vmcnt(4)" ::: "memory");
    __builtin_amdgcn_s_barrier();

    for (int t = 0; t < NT; ++t) {
        Ab = lds + (t & 1) * 32768 + wm * 16384 + lof;
        Bb = lds + BOFF + (t & 1) * 32768 + (wn >> 1) * 16384 + lof;

        LDA_(0); LDB_(0);
        STAGE(t + 1, 0, 0);
        asm volatile("s_waitcnt lgkmcnt(8)" ::: "memory");
        SYNC_IN();
        __builtin_amdgcn_s_setprio(1);
        MMA_(0, 0);
        SYNC_OUT();

        LDB_(1);
        STAGE(t + 1, 0, 1);
        SYNC_IN();
        __builtin_amdgcn_s_setprio(1);
        MMA_(0, 1);
        SYNC_OUT();

        LDA_(1);
        STAGE(t + 2, 1, 0);
        SYNC_IN();
        __builtin_amdgcn_s_setprio(1);
        MMA_(1, 1);
        SYNC_OUT();

        STAGE(t + 2, 1, 1);
        __builtin_amdgcn_sched_barrier(0);
        __builtin_amdgcn_s_barrier();
        asm volatile("s_waitcnt lgkmcnt(0)" ::: "memory");
        __builtin_amdgcn_sched_barrier(0);
        __builtin_amdgcn_s_setprio(1);
        MMA_(1, 0);
        __builtin_amdgcn_s_setprio(0);
        __builtin_amdgcn_sched_barrier(0);
        if (t < NT - 2)       asm volatile("s_waitcnt vmcnt(4)" ::: "memory");
        else if (t == NT - 2) asm volatile("s_waitcnt vmcnt(0)" ::: "memory");
        __builtin_amdgcn_s_barrier();
    }

    // ---- epilogue: bias+relu in reg, LDS transpose (2 passes of 128 KiB),
    //      fully-coalesced float4 stores (1 KiB contiguous per wave-inst) ----
    const int ocol = tn0 + wn * 64;
    float bv[4];
#pragma unroll
    for (int fn = 0; fn < 4; ++fn) bv[fn] = bias[ocol + fn * 16 + l15];
    float* lf = (float*)lds;
#pragma unroll
    for (int p = 0; p < 2; ++p) {
        if (wm == p) {
#pragma unroll
            for (int fm = 0; fm < 8; ++fm)
#pragma unroll
                for (int fn = 0; fn < 4; ++fn) {
                    const int col  = wn * 64 + fn * 16 + l15;
                    const int row0 = fm * 16 + lhi * 4;
#pragma unroll
                    for (int r = 0; r < 4; ++r) {
                        float v = acc[fm][fn][r] + bv[fn];
                        lf[(row0 + r) * 256 + col] = v > 0.f ? v : 0.f;
                    }
                }
        }
        __syncthreads();
        const float4* ls = (const float4*)lds;
#pragma unroll
        for (int s = 0; s < 16; ++s) {
            int i = s * 512 + tid;        // 8192 float4 = 128 KiB
            int row = i >> 6;             // 64 float4 per 256-f32 row
            int col = (i & 63) * 4;
            *(float4*)(O + (size_t)(tm0 + p * 128 + row) * N + (tn0 + col)) = ls[i];
        }
        if (p == 0) __syncthreads();      // pass-0 reads done before pass-1 writes
    }
}

// ---------------- launch ----------------

extern "C" void kernel_launch(void* const* d_in, const int* in_sizes, int n_in,
                              void* d_out, int out_size, void* d_ws, size_t ws_size,
                              hipStream_t stream) {
    const float* x    = (const float*)d_in[0];   // [8192, 8192]
    const float* W    = (const float*)d_in[1];   // [8192, 1024]
    const float* bias = (const float*)d_in[2];   // [8192]
    float* out = (float*)d_out;                  // [8192, 8192] fp32

    char* ws = (char*)d_ws;
    u16* xb = (u16*)ws;                                        // 134217728 B
    u16* wt = (u16*)(ws + 134217728);                          // [1024][8192]
    u16* wb = (u16*)(ws + 134217728 + 16777216);               // [8192][1024]
    u16* hb = (u16*)(ws + 134217728 + 2 * 16777216);           // [8192][1024]

    cvt_x_kernel<<<(BATCH * NFEAT / 8) / 256, 256, 0, stream>>>(x, xb);
    cvt_w_kernel<<<dim3(NFEAT / 64, DMODEL / 64), 256, 0, stream>>>(W, wb, wt);

    gemm1_8phase<<<dim3((BATCH / 256) * (DMODEL / 128)), 512, 0, stream>>>(
        xb, wt, hb, DMODEL, NFEAT);

    gemm2_8phase<<<dim3((BATCH / 256) * (NFEAT / 256)), 512, 0, stream>>>(
        hb, wb, out, bias, NFEAT, DMODEL);
}

// Round 5
// 384.665 us; speedup vs baseline: 1.0743x; 1.0743x over previous
//
#include <hip/hip_runtime.h>
#include <hip/hip_bf16.h>
#include <stdint.h>

#define BATCH  8192
#define NFEAT  8192
#define DMODEL 1024

typedef unsigned short u16;
typedef __attribute__((ext_vector_type(8))) short  short8;
typedef __attribute__((ext_vector_type(4))) float  f32x4;

// fp32 -> bf16 round-to-nearest-even
__device__ __forceinline__ u16 f2b(float f) {
    uint32_t u = __float_as_uint(f);
    u += 0x7fffu + ((u >> 16) & 1u);
    return (u16)(u >> 16);
}

// async global->LDS, 16B per lane; LDS dest is wave-uniform base + lane*16 (HW rule)
__device__ __forceinline__ void gld16(const u16* g, void* l) {
    __builtin_amdgcn_global_load_lds(
        (const __attribute__((address_space(1))) void*)(uintptr_t)g,
        (__attribute__((address_space(3))) void*)(uint32_t)(uintptr_t)l,
        16, 0, 0);
}

// ---------------- conversion kernels ----------------

__global__ void cvt_x_kernel(const float* __restrict__ x, u16* __restrict__ xb) {
    int i = blockIdx.x * blockDim.x + threadIdx.x;
    const float4* xv = (const float4*)x;
    float4 a = xv[2 * i];
    float4 b = xv[2 * i + 1];
    union { u16 u[8]; uint4 v; } o;
    o.u[0] = f2b(a.x); o.u[1] = f2b(a.y); o.u[2] = f2b(a.z); o.u[3] = f2b(a.w);
    o.u[4] = f2b(b.x); o.u[5] = f2b(b.y); o.u[6] = f2b(b.z); o.u[7] = f2b(b.w);
    ((uint4*)xb)[i] = o.v;
}

__global__ void cvt_w_kernel(const float* __restrict__ W,
                             u16* __restrict__ wb, u16* __restrict__ wt) {
    __shared__ u16 tile[64][65];
    const int f0 = blockIdx.x * 64;
    const int d0 = blockIdx.y * 64;
    const int t  = threadIdx.x;
#pragma unroll
    for (int rep = 0; rep < 16; ++rep) {
        int idx = rep * 256 + t;
        int r = idx >> 6, c = idx & 63;
        float v = W[(size_t)(f0 + r) * DMODEL + d0 + c];
        u16 u = f2b(v);
        tile[r][c] = u;
        wb[(size_t)(f0 + r) * DMODEL + d0 + c] = u;
    }
    __syncthreads();
#pragma unroll
    for (int rep = 0; rep < 16; ++rep) {
        int idx = rep * 256 + t;
        int r = idx >> 6, c = idx & 63;
        wt[(size_t)(d0 + r) * NFEAT + f0 + c] = tile[c][r];
    }
}

#define SYNC_IN()  do { __builtin_amdgcn_sched_barrier(0); __builtin_amdgcn_s_barrier(); \
                        asm volatile("s_waitcnt lgkmcnt(0)" ::: "memory");               \
                        __builtin_amdgcn_sched_barrier(0); } while (0)
#define SYNC_OUT() do { __builtin_amdgcn_s_setprio(0); __builtin_amdgcn_sched_barrier(0); \
                        __builtin_amdgcn_s_barrier(); } while (0)

// ---------------- GEMM 1: 256x128 tile, 8-phase, A 3-buf (2 tiles ahead) ----------------
// H = A @ B^T (bf16 out). A [M][K], B [N][K]. Grid = (M/256)*(N/128) = 256 blocks.
// LDS 128 KiB: A 3buf x 32 KiB @0, B 2buf x 16 KiB @98304.
__global__ __launch_bounds__(512, 2)
void gemm1_8phase(const u16* __restrict__ A, const u16* __restrict__ B,
                  u16* __restrict__ H, int N, int K) {
    const int NT = K >> 6;
    __shared__ __align__(1024) char lds[131072];
    const int BOFF = 98304;

    const int tid  = threadIdx.x;
    const int lane = tid & 63;
    const int wave = tid >> 6;             // 0..7
    const int wm   = wave >> 2;            // 0..1 (128-row half)
    const int wn   = wave & 3;             // 0..3 (32-col group)

    const int nwg = gridDim.x;
    const int swz = (blockIdx.x & 7) * (nwg >> 3) + (blockIdx.x >> 3);
    const int ntn = N >> 7;                // n-blocks (8)
    const int tm0 = (swz / ntn) << 8;
    const int tn0 = (swz % ntn) << 7;

    const int srl = lane >> 2;
    const int sch = (lane & 3) ^ (((lane >> 5) & 1) << 1);
    const int scol  = (wave & 1) * 32 + sch * 8;
    const int srow0 = (wave >> 1) * 16 + srl;

    const u16* pa[2][2];
    pa[0][0] = A + (size_t)(tm0 + srow0)            * K + scol;
    pa[0][1] = A + (size_t)(tm0 + srow0 + 64)       * K + scol;
    pa[1][0] = A + (size_t)(tm0 + 128 + srow0)      * K + scol;
    pa[1][1] = A + (size_t)(tm0 + 128 + srow0 + 64) * K + scol;
    const u16* pb[2];
    pb[0] = B + (size_t)(tn0 + srow0)      * K + scol;
    pb[1] = B + (size_t)(tn0 + srow0 + 64) * K + scol;

    auto STAGE_A = [&](int tau, int half) {
        if (tau < NT) {
            char* d = lds + (tau % 3) * 32768 + half * 16384 + wave * 1024;
            gld16(pa[half][0] + (size_t)tau * 64, d);
            gld16(pa[half][1] + (size_t)tau * 64, d + 8192);
        }
    };
    auto STAGE_B = [&](int tau) {
        if (tau < NT) {
            char* d = lds + BOFF + (tau & 1) * 16384 + wave * 1024;
            gld16(pb[0] + (size_t)tau * 64, d);
            gld16(pb[1] + (size_t)tau * 64, d + 8192);
        }
    };

    const int l15 = lane & 15, lhi = lane >> 4;
    const int pch = lhi ^ (((lane >> 3) & 1) << 1);
    const int lof = l15 * 64 + pch * 16;

    short8 a[4][2];
    short8 b[2][2];
    f32x4  acc[8][2] = {};

    const char* Ab;
    const char* Bb;
    auto LDA_ = [&](int mh) {
#pragma unroll
        for (int fm = 0; fm < 4; ++fm)
#pragma unroll
            for (int ks = 0; ks < 2; ++ks)
                a[fm][ks] = *(const short8*)(Ab + ((mh * 4 + fm) * 2 + ks) * 1024);
    };
    auto LDB_ = [&](int nh) {
#pragma unroll
        for (int ks = 0; ks < 2; ++ks)
            b[nh][ks] = *(const short8*)(Bb + (nh * 2 + ks) * 1024);
    };
    auto MMA_ = [&](int mh, int nh) {
#pragma unroll
        for (int ks = 0; ks < 2; ++ks)
#pragma unroll
            for (int fm = 0; fm < 4; ++fm)
                acc[mh * 4 + fm][nh] = __builtin_amdgcn_mfma_f32_16x16x32_bf16(
                    a[fm][ks], b[nh][ks], acc[mh * 4 + fm][nh], 0, 0, 0);
    };

    // prologue: tiles 0 and 1 in flight; drain tile 0 (keep A(1)4+B(1)2)
    STAGE_A(0, 0); STAGE_A(0, 1); STAGE_B(0);
    STAGE_A(1, 0); STAGE_A(1, 1); STAGE_B(1);
    asm volatile("s_waitcnt vmcnt(6)" ::: "memory");
    __builtin_amdgcn_s_barrier();

    for (int t = 0; t < NT; ++t) {
        Ab = lds + (t % 3) * 32768 + wm * 16384 + lof;
        Bb = lds + BOFF + (t & 1) * 16384 + wn * 4096 + lof;

        // q0: reads A[mh0](8)+B[nh0](2); stage A(t+2,h0) [buf (t+2)%3 holds A(t-1), reads done]
        LDA_(0); LDB_(0);
        STAGE_A(t + 2, 0);
        SYNC_IN();
        __builtin_amdgcn_s_setprio(1);
        MMA_(0, 0);
        SYNC_OUT();

        // q1: reads B[nh1](2); stage A(t+2,h1)
        LDB_(1);
        STAGE_A(t + 2, 1);
        SYNC_IN();
        __builtin_amdgcn_s_setprio(1);
        MMA_(0, 1);
        SYNC_OUT();

        // q2: reads A[mh1](8); stage B(t+2) [B buf t&1 last read q1 -> safe]
        LDA_(1);
        STAGE_B(t + 2);
        SYNC_IN();
        __builtin_amdgcn_s_setprio(1);
        MMA_(1, 1);
        SYNC_OUT();

        // q3
        __builtin_amdgcn_sched_barrier(0);
        __builtin_amdgcn_s_barrier();
        __builtin_amdgcn_s_setprio(1);
        MMA_(1, 0);
        __builtin_amdgcn_s_setprio(0);
        __builtin_amdgcn_sched_barrier(0);
        // queue: [A(t+1)4,B(t+1)2, A(t+2)4,B(t+2)2] -> drain (t+1), issued a full tile ago
        if (t < NT - 2)       asm volatile("s_waitcnt vmcnt(6)" ::: "memory");
        else if (t == NT - 2) asm volatile("s_waitcnt vmcnt(0)" ::: "memory");
        __builtin_amdgcn_s_barrier();
    }

    // epilogue: bf16 tile via LDS transpose, coalesced 16B stores (uses first 64 KiB)
    u16* lu = (u16*)lds;
#pragma unroll
    for (int fm = 0; fm < 8; ++fm)
#pragma unroll
        for (int nh = 0; nh < 2; ++nh) {
            const int col  = wn * 32 + nh * 16 + l15;
            const int row0 = wm * 128 + fm * 16 + lhi * 4;
#pragma unroll
            for (int r = 0; r < 4; ++r)
                lu[(row0 + r) * 128 + col] = f2b(acc[fm][nh][r]);
        }
    __syncthreads();
    const uint4* ls = (const uint4*)lds;
#pragma unroll
    for (int s = 0; s < 8; ++s) {
        int i = s * 512 + tid;
        int row = i >> 4;
        int col = (i & 15) * 8;
        *(uint4*)(H + (size_t)(tm0 + row) * N + (tn0 + col)) = ls[i];
    }
}

// ---------------- GEMM 2: 256x256 8-phase, A 3-buf (2 tiles ahead) ----------------
// out = relu(A @ B^T + bias), fp32 out. LDS 160 KiB: A 3x32K @0, B 2x32K @98304.
__global__ __launch_bounds__(512, 2)
void gemm2_8phase(const u16* __restrict__ A, const u16* __restrict__ B,
                  float* __restrict__ O, const float* __restrict__ bias,
                  int N, int K) {
    const int NT = K >> 6;
    __shared__ __align__(1024) char lds[163840];
    const int BOFF = 98304;

    const int tid  = threadIdx.x;
    const int lane = tid & 63;
    const int wave = tid >> 6;
    const int wm   = wave >> 2;
    const int wn   = wave & 3;

    const int nwg = gridDim.x;
    const int swz = (blockIdx.x & 7) * (nwg >> 3) + (blockIdx.x >> 3);
    const int ntn = N >> 8;
    const int tm0 = (swz / ntn) << 8;
    const int tn0 = (swz % ntn) << 8;

    const int srl = lane >> 2;
    const int sch = (lane & 3) ^ (((lane >> 5) & 1) << 1);
    const int scol  = (wave & 1) * 32 + sch * 8;
    const int srow0 = (wave >> 1) * 16 + srl;

    const u16* pa[2][2];
    const u16* pb[2][2];
    pa[0][0] = A + (size_t)(tm0 + srow0)       * K + scol;
    pa[0][1] = A + (size_t)(tm0 + srow0 + 64)  * K + scol;
    pa[1][0] = A + (size_t)(tm0 + 128 + srow0)      * K + scol;
    pa[1][1] = A + (size_t)(tm0 + 128 + srow0 + 64) * K + scol;
    pb[0][0] = B + (size_t)(tn0 + srow0)       * K + scol;
    pb[0][1] = B + (size_t)(tn0 + srow0 + 64)  * K + scol;
    pb[1][0] = B + (size_t)(tn0 + 128 + srow0)      * K + scol;
    pb[1][1] = B + (size_t)(tn0 + 128 + srow0 + 64) * K + scol;

    auto STAGE_A = [&](int tau, int half) {
        if (tau < NT) {
            char* d = lds + (tau % 3) * 32768 + half * 16384 + wave * 1024;
            gld16(pa[half][0] + (size_t)tau * 64, d);
            gld16(pa[half][1] + (size_t)tau * 64, d + 8192);
        }
    };
    auto STAGE_B = [&](int tau, int half) {
        if (tau < NT) {
            char* d = lds + BOFF + (tau & 1) * 32768 + half * 16384 + wave * 1024;
            gld16(pb[half][0] + (size_t)tau * 64, d);
            gld16(pb[half][1] + (size_t)tau * 64, d + 8192);
        }
    };

    const int l15 = lane & 15, lhi = lane >> 4;
    const int pch = lhi ^ (((lane >> 3) & 1) << 1);
    const int lof = l15 * 64 + pch * 16;

    short8 a[4][2];
    short8 b[4][2];
    f32x4  acc[8][4] = {};

    const char* Ab;
    const char* Bb;
    auto LDA_ = [&](int mh) {
#pragma unroll
        for (int fm = 0; fm < 4; ++fm)
#pragma unroll
            for (int ks = 0; ks < 2; ++ks)
                a[fm][ks] = *(const short8*)(Ab + ((mh * 4 + fm) * 2 + ks) * 1024);
    };
    auto LDB_ = [&](int nh) {
#pragma unroll
        for (int fn = 0; fn < 2; ++fn)
#pragma unroll
            for (int ks = 0; ks < 2; ++ks)
                b[nh * 2 + fn][ks] = *(const short8*)(Bb + (((wn & 1) * 4 + nh * 2 + fn) * 2 + ks) * 1024);
    };
    auto MMA_ = [&](int mh, int nh) {
#pragma unroll
        for (int ks = 0; ks < 2; ++ks)
#pragma unroll
            for (int fm = 0; fm < 4; ++fm)
#pragma unroll
                for (int fn = 0; fn < 2; ++fn)
                    acc[mh * 4 + fm][nh * 2 + fn] = __builtin_amdgcn_mfma_f32_16x16x32_bf16(
                        a[fm][ks], b[nh * 2 + fn][ks], acc[mh * 4 + fm][nh * 2 + fn], 0, 0, 0);
    };

    // prologue: tiles 0 and 1 fully in flight; drain tile 0 (keep tile 1's 8)
    STAGE_A(0, 0); STAGE_A(0, 1); STAGE_B(0, 0); STAGE_B(0, 1);
    STAGE_A(1, 0); STAGE_A(1, 1); STAGE_B(1, 0); STAGE_B(1, 1);
    asm volatile("s_waitcnt vmcnt(8)" ::: "memory");
    __builtin_amdgcn_s_barrier();

    for (int t = 0; t < NT; ++t) {
        Ab = lds + (t % 3) * 32768 + wm * 16384 + lof;
        Bb = lds + BOFF + (t & 1) * 32768 + (wn >> 1) * 16384 + lof;

        // q0: reads A[mh0](8)+B[nh0](4); stage A(t+2,h0)
        LDA_(0); LDB_(0);
        STAGE_A(t + 2, 0);
        asm volatile("s_waitcnt lgkmcnt(8)" ::: "memory");
        SYNC_IN();
        __builtin_amdgcn_s_setprio(1);
        MMA_(0, 0);
        SYNC_OUT();

        // q1: reads B[nh1](4); stage A(t+2,h1)
        LDB_(1);
        STAGE_A(t + 2, 1);
        SYNC_IN();
        __builtin_amdgcn_s_setprio(1);
        MMA_(0, 1);
        SYNC_OUT();

        // q2: reads A[mh1](8); stage B(t+2,h0) [B buf t&1 last read q1 -> safe]
        LDA_(1);
        STAGE_B(t + 2, 0);
        SYNC_IN();
        __builtin_amdgcn_s_setprio(1);
        MMA_(1, 1);
        SYNC_OUT();

        // q3: stage B(t+2,h1)
        STAGE_B(t + 2, 1);
        __builtin_amdgcn_sched_barrier(0);
        __builtin_amdgcn_s_barrier();
        asm volatile("s_waitcnt lgkmcnt(0)" ::: "memory");
        __builtin_amdgcn_sched_barrier(0);
        __builtin_amdgcn_s_setprio(1);
        MMA_(1, 0);
        __builtin_amdgcn_s_setprio(0);
        __builtin_amdgcn_sched_barrier(0);
        // queue: [A(t+1)4,B(t+1)4, A(t+2)4,B(t+2)4] -> drain (t+1), issued a full tile ago
        if (t < NT - 2)       asm volatile("s_waitcnt vmcnt(8)" ::: "memory");
        else if (t == NT - 2) asm volatile("s_waitcnt vmcnt(0)" ::: "memory");
        __builtin_amdgcn_s_barrier();
    }

    // epilogue: direct fp32 relu(acc + bias) stores (round-3 form; RMW fetch not binding)
    const int orow = tm0 + wm * 128;
    const int ocol = tn0 + wn * 64;
    float bv[4];
#pragma unroll
    for (int fn = 0; fn < 4; ++fn) bv[fn] = bias[ocol + fn * 16 + l15];
#pragma unroll
    for (int fm = 0; fm < 8; ++fm) {
        const int row0 = orow + fm * 16 + lhi * 4;
#pragma unroll
        for (int fn = 0; fn < 4; ++fn) {
            const int col = ocol + fn * 16 + l15;
#pragma unroll
            for (int r = 0; r < 4; ++r) {
                float v = acc[fm][fn][r] + bv[fn];
                O[(size_t)(row0 + r) * N + col] = v > 0.f ? v : 0.f;
            }
        }
    }
}

// ---------------- launch ----------------

extern "C" void kernel_launch(void* const* d_in, const int* in_sizes, int n_in,
                              void* d_out, int out_size, void* d_ws, size_t ws_size,
                              hipStream_t stream) {
    const float* x    = (const float*)d_in[0];   // [8192, 8192]
    const float* W    = (const float*)d_in[1];   // [8192, 1024]
    const float* bias = (const float*)d_in[2];   // [8192]
    float* out = (float*)d_out;                  // [8192, 8192] fp32

    char* ws = (char*)d_ws;
    u16* xb = (u16*)ws;                                        // 134217728 B
    u16* wt = (u16*)(ws + 134217728);                          // [1024][8192]
    u16* wb = (u16*)(ws + 134217728 + 16777216);               // [8192][1024]
    u16* hb = (u16*)(ws + 134217728 + 2 * 16777216);           // [8192][1024]

    cvt_x_kernel<<<(BATCH * NFEAT / 8) / 256, 256, 0, stream>>>(x, xb);
    cvt_w_kernel<<<dim3(NFEAT / 64, DMODEL / 64), 256, 0, stream>>>(W, wb, wt);

    gemm1_8phase<<<dim3((BATCH / 256) * (DMODEL / 128)), 512, 0, stream>>>(
        xb, wt, hb, DMODEL, NFEAT);

    gemm2_8phase<<<dim3((BATCH / 256) * (NFEAT / 256)), 512, 0, stream>>>(
        hb, wb, out, bias, NFEAT, DMODEL);
}